// Round 4
// baseline (555.536 us; speedup 1.0000x reference)
//
#include <hip/hip_runtime.h>
#include <hip/hip_bf16.h>
#include <math.h>

#define N_NODES 50000
#define N_EDGES 800000
#define D0 64
#define D1 128
#define D2 40

#define NB  512   // buckets
#define NPB 98    // nodes per bucket (512*98 = 50176 >= 50000)
#define CAP 2048  // per-bucket edge capacity (mean 1562, ~12 sigma headroom)
#define PAD1 68   // agg1 LDS row stride (floats): 16B-aligned rows, spread banks
#define PAD2 41   // agg2 LDS row stride (floats): gcd(41,32)=1 -> conflict-free columns

typedef short s16x8 __attribute__((ext_vector_type(8)));
typedef float f32x4 __attribute__((ext_vector_type(4)));

static __device__ __forceinline__ unsigned short f2bf(float v) {
    __hip_bfloat16 hb = __float2bfloat16(v);
    return *(unsigned short*)&hb;
}

// ---------------- fused prep: LDS-aggregated bucket scatter + cast x + pack weights --------
__global__ __launch_bounds__(256) void prep_scatter_kernel(
        const float* __restrict__ x, const int* __restrict__ src, const int* __restrict__ dst,
        const float* __restrict__ W1l, const float* __restrict__ W1r,
        const float* __restrict__ W2l, const float* __restrict__ W2r,
        unsigned short* __restrict__ xh, int* __restrict__ gcur, unsigned* __restrict__ ebuf,
        unsigned short* __restrict__ wpk1, unsigned short* __restrict__ wpk2,
        int E, int nScat, int nCast) {
    int b = blockIdx.x, t = threadIdx.x;
    if (b < nScat) {
        __shared__ int h[NB];
        __shared__ int base[NB];
        int e0 = b * 4096;
        h[t] = 0; h[t + 256] = 0;
        __syncthreads();
        int dloc[16];
#pragma unroll
        for (int u = 0; u < 16; ++u) {
            int e = e0 + u * 256 + t;
            dloc[u] = (e < E) ? dst[e] : -1;
            if (dloc[u] >= 0) atomicAdd(&h[(unsigned)dloc[u] / NPB], 1);
        }
        __syncthreads();
        for (int u = t; u < NB; u += 256)
            if (h[u] > 0) base[u] = u * CAP + atomicAdd(&gcur[u], h[u]);
        __syncthreads();
        h[t] = 0; h[t + 256] = 0;
        __syncthreads();
#pragma unroll
        for (int u = 0; u < 16; ++u) {
            int e = e0 + u * 256 + t;
            if (dloc[u] >= 0) {
                unsigned d = (unsigned)dloc[u];
                unsigned bk = d / NPB;
                unsigned ld = d - bk * NPB;
                int k = atomicAdd(&h[bk], 1);
                ebuf[base[bk] + k] = (ld << 17) | (unsigned)src[e];
            }
        }
    } else if (b < nScat + nCast) {
        int i = ((b - nScat) * 256 + t) * 4;   // nCast*1024 == N*D0 exactly
        float4 v = *(const float4*)(x + i);
        unsigned o0 = (unsigned)f2bf(v.x) | ((unsigned)f2bf(v.y) << 16);
        unsigned o1 = (unsigned)f2bf(v.z) | ((unsigned)f2bf(v.w) << 16);
        uint2 pk; pk.x = o0; pk.y = o1;
        *(uint2*)(xh + i) = pk;
    } else if (b < nScat + nCast + 8) {
        int f = (b - nScat - nCast) * 4 + (t >> 6);   // 0..31
        int lane = t & 63;
        int nt = f & 7;
        int col = nt * 16 + (lane & 15);
        int kbase = (f >> 3) * 32 + (lane >> 4) * 8;
        unsigned short* o = wpk1 + ((size_t)f * 64 + lane) * 8;
#pragma unroll
        for (int j = 0; j < 8; ++j) {
            int k = kbase + j;
            float w = (k < 64) ? W1r[k * 128 + col] : W1l[(k - 64) * 128 + col];
            o[j] = f2bf(w);
        }
    } else {
        int f = (b - nScat - nCast - 8) * 4 + (t >> 6);   // 0..19
        if (f < 20) {
            int lane = t & 63;
            int nt = f % 5;
            int col = nt * 16 + (lane & 15);       // 0..79
            int kbase = (f / 5) * 32 + (lane >> 4) * 8;
            unsigned short* o = wpk2 + ((size_t)f * 64 + lane) * 8;
#pragma unroll
            for (int j = 0; j < 8; ++j) {
                int k = kbase + j;
                float w = (col < 40) ? W2l[k * 40 + col] : W2r[k * 40 + (col - 40)];
                o[j] = f2bf(w);
            }
        }
    }
}

// ---------------- agg1: one block per bucket, LDS f32 accumulators, unordered edges -------
__global__ __launch_bounds__(256) void agg1_bucket(
        const unsigned short* __restrict__ xh, const unsigned* __restrict__ ebuf,
        const int* __restrict__ gcur, unsigned short* __restrict__ aggh, int N) {
    __shared__ float acc[NPB][PAD1];
    __shared__ int degL[NPB];
    int b = blockIdx.x, t = threadIdx.x;
    for (int i = t; i < NPB * PAD1; i += 256) ((float*)acc)[i] = 0.f;
    if (t < NPB) degL[t] = 0;
    __syncthreads();
    int ne = gcur[b]; ne = (ne < CAP) ? ne : CAP;
    const unsigned* eb = ebuf + (size_t)b * CAP;
    int l = t & 7;          // lane-in-edge (8 dims each)
    int g = t >> 3;         // edge slot 0..31 per iteration
    for (int i0 = 0; i0 < ne; i0 += 128) {
        unsigned pk[4]; uint4 v[4]; bool val[4];
#pragma unroll
        for (int u = 0; u < 4; ++u) {
            int e = i0 + u * 32 + g;
            val[u] = e < ne;
            pk[u] = eb[val[u] ? e : 0];
            int sid = val[u] ? (int)(pk[u] & 0x1FFFFu) : 0;
            v[u] = *(const uint4*)(xh + (size_t)sid * D0 + l * 8);
        }
#pragma unroll
        for (int u = 0; u < 4; ++u) {
            if (val[u]) {
                int ld = (int)(pk[u] >> 17);
                float* a = &acc[ld][l * 8];
                atomicAdd(&a[0], __uint_as_float(v[u].x << 16));
                atomicAdd(&a[1], __uint_as_float(v[u].x & 0xffff0000u));
                atomicAdd(&a[2], __uint_as_float(v[u].y << 16));
                atomicAdd(&a[3], __uint_as_float(v[u].y & 0xffff0000u));
                atomicAdd(&a[4], __uint_as_float(v[u].z << 16));
                atomicAdd(&a[5], __uint_as_float(v[u].z & 0xffff0000u));
                atomicAdd(&a[6], __uint_as_float(v[u].w << 16));
                atomicAdd(&a[7], __uint_as_float(v[u].w & 0xffff0000u));
                if (l == 0) atomicAdd(&degL[ld], 1);
            }
        }
    }
    __syncthreads();
    // finalize: 98 nodes x 8 dim-groups; pack mean to bf16
    for (int i = t; i < NPB * 8; i += 256) {
        int n = i >> 3, l8 = (i & 7) * 8;
        int node = b * NPB + n;
        if (node >= N) continue;
        float inv = 1.f / (float)max(degL[n], 1);
        const float* a = &acc[n][l8];
        unsigned o0 = (unsigned)f2bf(a[0] * inv) | ((unsigned)f2bf(a[1] * inv) << 16);
        unsigned o1 = (unsigned)f2bf(a[2] * inv) | ((unsigned)f2bf(a[3] * inv) << 16);
        unsigned o2 = (unsigned)f2bf(a[4] * inv) | ((unsigned)f2bf(a[5] * inv) << 16);
        unsigned o3 = (unsigned)f2bf(a[6] * inv) | ((unsigned)f2bf(a[7] * inv) << 16);
        uint4 pk; pk.x = o0; pk.y = o1; pk.z = o2; pk.w = o3;
        *(uint4*)(aggh + (size_t)node * D0 + l8) = pk;
    }
}

// ---------------- agg2: one block per bucket, LDS acc + fused mean/r2/log_softmax ---------
__global__ __launch_bounds__(256) void agg2_bucket(
        const unsigned short* __restrict__ p2h, const float* __restrict__ r2,
        const unsigned* __restrict__ ebuf, const int* __restrict__ gcur,
        float* __restrict__ out, float* __restrict__ out2, int N) {
    __shared__ float acc[NPB][PAD2];
    __shared__ int degL[NPB];
    int b = blockIdx.x, t = threadIdx.x;
    for (int i = t; i < NPB * PAD2; i += 256) ((float*)acc)[i] = 0.f;
    if (t < NPB) degL[t] = 0;
    __syncthreads();
    int ne = gcur[b]; ne = (ne < CAP) ? ne : CAP;
    const unsigned* eb = ebuf + (size_t)b * CAP;
    int g = t / 5;          // edge slot 0..50 (t==255 -> g==51 idle)
    int l = t - g * 5;      // 0..4 (8 dims each)
    bool gv = g < 51;
    for (int i0 = 0; i0 < ne; i0 += 204) {
        unsigned pk[4]; uint4 v[4]; bool val[4];
#pragma unroll
        for (int u = 0; u < 4; ++u) {
            int e = i0 + u * 51 + g;
            val[u] = gv && (e < ne);
            pk[u] = eb[val[u] ? e : 0];
            int sid = val[u] ? (int)(pk[u] & 0x1FFFFu) : 0;
            v[u] = *(const uint4*)(p2h + (size_t)sid * 64 + l * 8);
        }
#pragma unroll
        for (int u = 0; u < 4; ++u) {
            if (val[u]) {
                int ld = (int)(pk[u] >> 17);
                float* a = &acc[ld][l * 8];
                atomicAdd(&a[0], __uint_as_float(v[u].x << 16));
                atomicAdd(&a[1], __uint_as_float(v[u].x & 0xffff0000u));
                atomicAdd(&a[2], __uint_as_float(v[u].y << 16));
                atomicAdd(&a[3], __uint_as_float(v[u].y & 0xffff0000u));
                atomicAdd(&a[4], __uint_as_float(v[u].z << 16));
                atomicAdd(&a[5], __uint_as_float(v[u].z & 0xffff0000u));
                atomicAdd(&a[6], __uint_as_float(v[u].w << 16));
                atomicAdd(&a[7], __uint_as_float(v[u].w & 0xffff0000u));
                if (l == 0) atomicAdd(&degL[ld], 1);
            }
        }
    }
    __syncthreads();
    // finalize: thread-per-node; LDS col reads are conflict-free (stride 41)
    if (t < NPB) {
        int node = b * NPB + t;
        if (node < N) {
            float inv = 1.f / (float)max(degL[t], 1);
            const float* rr = r2 + (size_t)node * D2;
            float* ha = acc[t];
            float m = -INFINITY;
            for (int d = 0; d < D2; ++d) {
                float h = rr[d] + ha[d] * inv;
                ha[d] = h;
                out[(size_t)node * D2 + d] = h;
                m = fmaxf(m, h);
            }
            float s = 0.f;
            for (int d = 0; d < D2; ++d) s += expf(ha[d] - m);
            float lg = m + logf(s);
            for (int d = 0; d < D2; ++d)
                out2[(size_t)node * D2 + d] = ha[d] - lg;
        }
    }
}

// ---------------- fused GEMM (64-row tiles): h=relu([x|agg]@[W1r;W1l]+b1) staged in LDS,
//                  then p2h(bf16,stride64)=h@W2l ; r2(f32)=h@W2r+b2 ----------------
// Each wave owns LDS rows [w*16, w*16+16) exclusively after the initial barrier.
__global__ __launch_bounds__(256) void gemm_fused(
        const unsigned short* __restrict__ xh, const unsigned short* __restrict__ aggh,
        const unsigned short* __restrict__ Wpk1, const unsigned short* __restrict__ Wpk2,
        const float* __restrict__ b1, const float* __restrict__ b2,
        unsigned short* __restrict__ p2h, float* __restrict__ r2, int N) {
    __shared__ __align__(16) unsigned short As[64 * 136];  // [row][k], +8 pad
    int t = threadIdx.x;
    int r0 = blockIdx.x * 64;
    for (int i = t; i < 1024; i += 256) {
        int r = i >> 4, c = i & 15;
        int gr = r0 + r; gr = (gr < N) ? gr : (N - 1);
        uint4 v = (c < 8) ? ((const uint4*)(xh + (size_t)gr * 64))[c]
                          : ((const uint4*)(aggh + (size_t)gr * 64))[c - 8];
        *(uint4*)(As + r * 136 + c * 8) = v;
    }
    __syncthreads();
    int w = t >> 6, lane = t & 63;
    int l15 = lane & 15, q = lane >> 4;
    f32x4 zero = {0.f, 0.f, 0.f, 0.f};
    const unsigned short* abase = As + (w * 16 + l15) * 136 + q * 8;

    // ---- phase 1: [x|agg] @ [W1r;W1l] ----
    f32x4 acc[8];
#pragma unroll
    for (int nt = 0; nt < 8; ++nt) acc[nt] = zero;
#pragma unroll
    for (int ks = 0; ks < 4; ++ks) {
        s16x8 a0 = *(const s16x8*)(abase + ks * 32);
        s16x8 b[8];
#pragma unroll
        for (int nt = 0; nt < 8; ++nt)
            b[nt] = *(const s16x8*)(Wpk1 + ((size_t)(ks * 8 + nt) * 64 + lane) * 8);
#pragma unroll
        for (int nt = 0; nt < 8; ++nt)
            acc[nt] = __builtin_amdgcn_mfma_f32_16x16x32_bf16(a0, b[nt], acc[nt], 0, 0, 0);
    }
    // ---- stage h = relu(acc + b1) back into As (wave-private rows) ----
    int rloc = w * 16 + q * 4;
#pragma unroll
    for (int nt = 0; nt < 8; ++nt) {
        int col = nt * 16 + l15;
        float bias = b1[col];
#pragma unroll
        for (int reg = 0; reg < 4; ++reg)
            As[(rloc + reg) * 136 + col] = f2bf(fmaxf(acc[nt][reg] + bias, 0.f));
    }
    // ---- phase 2: h @ [W2l|W2r] ----
    f32x4 acc2[5];
#pragma unroll
    for (int nt = 0; nt < 5; ++nt) acc2[nt] = zero;
#pragma unroll
    for (int ks = 0; ks < 4; ++ks) {
        s16x8 a0 = *(const s16x8*)(abase + ks * 32);
        s16x8 b[5];
#pragma unroll
        for (int nt = 0; nt < 5; ++nt)
            b[nt] = *(const s16x8*)(Wpk2 + ((size_t)(ks * 5 + nt) * 64 + lane) * 8);
#pragma unroll
        for (int nt = 0; nt < 5; ++nt)
            acc2[nt] = __builtin_amdgcn_mfma_f32_16x16x32_bf16(a0, b[nt], acc2[nt], 0, 0, 0);
    }
    int rbase = r0 + w * 16 + q * 4;
#pragma unroll
    for (int nt = 0; nt < 5; ++nt) {
        int col = nt * 16 + l15;   // 0..79
        bool isp = col < 40;
        int oc = isp ? col : (col - 40);
        float bias = isp ? 0.f : b2[oc];
#pragma unroll
        for (int reg = 0; reg < 4; ++reg) {
            int row = rbase + reg;
            if (row < N) {
                float v = acc2[nt][reg] + bias;
                if (isp) p2h[(size_t)row * 64 + oc] = f2bf(v);
                else     r2[(size_t)row * D2 + oc] = v;
            }
        }
    }
}

// ---------------- launch ----------------

extern "C" void kernel_launch(void* const* d_in, const int* in_sizes, int n_in,
                              void* d_out, int out_size, void* d_ws, size_t ws_size,
                              hipStream_t stream) {
    const float* x   = (const float*)d_in[0];
    const int*   ei  = (const int*)d_in[1];
    const float* W1l = (const float*)d_in[2];
    const float* W1r = (const float*)d_in[3];
    const float* b1  = (const float*)d_in[4];
    const float* W2l = (const float*)d_in[5];
    const float* W2r = (const float*)d_in[6];
    const float* b2  = (const float*)d_in[7];
    float* out = (float*)d_out;

    const int N = N_NODES;
    const int E = in_sizes[1] / 2;
    const int* src = ei;
    const int* dst = ei + E;

    char* p = (char*)d_ws;
    auto alloc = [&](size_t bytes) -> void* {
        void* r = (void*)p;
        p += (bytes + 255) & ~(size_t)255;
        return r;
    };
    const int nScat = (E + 4095) / 4096;           // 196
    const int nCast = (N * D0) / 1024;             // 3125 (exact)

    unsigned* ebuf = (unsigned*)alloc((size_t)NB * CAP * 4);   // 4 MB, bucket-padded
    int*      gcur = (int*)alloc(NB * 4);
    unsigned short* xh    = (unsigned short*)alloc((size_t)N * D0 * 2);
    unsigned short* aggh  = (unsigned short*)alloc((size_t)N * D0 * 2);
    unsigned short* wpk1  = (unsigned short*)alloc((size_t)32 * 64 * 8 * 2);
    unsigned short* wpk2  = (unsigned short*)alloc((size_t)20 * 64 * 8 * 2);
    unsigned short* p2h   = (unsigned short*)alloc((size_t)N * 64 * 2);   // 128 B stride
    float* r2buf = (float*)alloc((size_t)N * D2 * 4);

    // zero bucket cursors, then fused prep (LDS-aggregated scatter + cast + pack)
    hipMemsetAsync(gcur, 0, NB * sizeof(int), stream);
    prep_scatter_kernel<<<nScat + nCast + 8 + 5, 256, 0, stream>>>(
        x, src, dst, W1l, W1r, W2l, W2r, xh, gcur, ebuf, wpk1, wpk2, E, nScat, nCast);

    // layer 1: bucket-parallel LDS aggregation, then fused GEMM1+ReLU+GEMM2
    agg1_bucket<<<NB, 256, 0, stream>>>(xh, ebuf, gcur, aggh, N);
    gemm_fused<<<(N + 63) / 64, 256, 0, stream>>>(xh, aggh, wpk1, wpk2, b1, b2,
                                                  p2h, r2buf, N);

    // layer 2: bucket-parallel aggregation of projected features + fused log_softmax
    agg2_bucket<<<NB, 256, 0, stream>>>(p2h, r2buf, ebuf, gcur,
                                        out, out + (size_t)N * D2, N);
}

// Round 6
// 169.592 us; speedup vs baseline: 3.2757x; 3.2757x over previous
//
#include <hip/hip_runtime.h>
#include <hip/hip_bf16.h>
#include <math.h>

#define N_NODES 50000
#define D0 64
#define D1 128
#define D2 40

#define NB  1024  // buckets
#define NPB 49    // nodes per bucket (1024*49 = 50176 >= 50000)
#define CAP 1024  // per-bucket edge capacity (mean 781, ~8.7 sigma headroom)

typedef short s16x8 __attribute__((ext_vector_type(8)));
typedef float f32x4 __attribute__((ext_vector_type(4)));

static __device__ __forceinline__ unsigned short f2bf(float v) {
    __hip_bfloat16 hb = __float2bfloat16(v);
    return *(unsigned short*)&hb;
}

// ---------------- fused prep: LDS-aggregated bucket scatter + cast x + pack weights --------
__global__ __launch_bounds__(256) void prep_scatter_kernel(
        const float* __restrict__ x, const int* __restrict__ src, const int* __restrict__ dst,
        const float* __restrict__ W1l, const float* __restrict__ W1r,
        const float* __restrict__ W2l, const float* __restrict__ W2r,
        unsigned short* __restrict__ xh, int* __restrict__ gcur, unsigned* __restrict__ ebuf,
        unsigned short* __restrict__ wpk1, unsigned short* __restrict__ wpk2,
        int E, int nScat, int nCast) {
    int b = blockIdx.x, t = threadIdx.x;
    if (b < nScat) {
        __shared__ int h[NB];
        __shared__ int base[NB];
        int e0 = b * 4096;
        h[t] = 0; h[t + 256] = 0; h[t + 512] = 0; h[t + 768] = 0;
        __syncthreads();
        int dloc[16];
#pragma unroll
        for (int u = 0; u < 16; ++u) {
            int e = e0 + u * 256 + t;
            dloc[u] = (e < E) ? dst[e] : -1;
            if (dloc[u] >= 0) atomicAdd(&h[(unsigned)dloc[u] / NPB], 1);
        }
        __syncthreads();
        for (int u = t; u < NB; u += 256)
            if (h[u] > 0) base[u] = u * CAP + atomicAdd(&gcur[u], h[u]);
        __syncthreads();
        h[t] = 0; h[t + 256] = 0; h[t + 512] = 0; h[t + 768] = 0;
        __syncthreads();
#pragma unroll
        for (int u = 0; u < 16; ++u) {
            int e = e0 + u * 256 + t;
            if (dloc[u] >= 0) {
                unsigned d = (unsigned)dloc[u];
                unsigned bk = d / NPB;
                unsigned ld = d - bk * NPB;
                int k = atomicAdd(&h[bk], 1);
                ebuf[base[bk] + k] = (ld << 17) | (unsigned)src[e];
            }
        }
    } else if (b < nScat + nCast) {
        int i = ((b - nScat) * 256 + t) * 4;   // nCast*1024 == N*D0 exactly
        float4 v = *(const float4*)(x + i);
        unsigned o0 = (unsigned)f2bf(v.x) | ((unsigned)f2bf(v.y) << 16);
        unsigned o1 = (unsigned)f2bf(v.z) | ((unsigned)f2bf(v.w) << 16);
        uint2 pk; pk.x = o0; pk.y = o1;
        *(uint2*)(xh + i) = pk;
    } else if (b < nScat + nCast + 8) {
        int f = (b - nScat - nCast) * 4 + (t >> 6);   // 0..31
        int lane = t & 63;
        int nt = f & 7;
        int col = nt * 16 + (lane & 15);
        int kbase = (f >> 3) * 32 + (lane >> 4) * 8;
        unsigned short* o = wpk1 + ((size_t)f * 64 + lane) * 8;
#pragma unroll
        for (int j = 0; j < 8; ++j) {
            int k = kbase + j;
            float w = (k < 64) ? W1r[k * 128 + col] : W1l[(k - 64) * 128 + col];
            o[j] = f2bf(w);
        }
    } else {
        int f = (b - nScat - nCast - 8) * 4 + (t >> 6);   // 0..19
        if (f < 20) {
            int lane = t & 63;
            int nt = f % 5;
            int col = nt * 16 + (lane & 15);       // 0..79
            int kbase = (f / 5) * 32 + (lane >> 4) * 8;
            unsigned short* o = wpk2 + ((size_t)f * 64 + lane) * 8;
#pragma unroll
            for (int j = 0; j < 8; ++j) {
                int k = kbase + j;
                float w = (col < 40) ? W2l[k * 40 + col] : W2r[k * 40 + (col - 40)];
                o[j] = f2bf(w);
            }
        }
    }
}

// ---------------- fused fill+agg1: per-bucket LDS counting-sort -> local CSR -> aggregate --
// One block per bucket. Edge values held in registers across the two passes; counting
// uses int LDS atomics (cheap); aggregation is node-per-wave with register accumulators.
__global__ __launch_bounds__(256) void fillagg1_kernel(
        const unsigned short* __restrict__ xh, const unsigned* __restrict__ ebuf,
        const int* __restrict__ gcur,
        int* __restrict__ rowstart, int* __restrict__ rowcnt, int* __restrict__ csr,
        unsigned short* __restrict__ aggh, int N) {
    __shared__ int csr_l[CAP];
    __shared__ int cnt[64];
    __shared__ int sd[64];
    __shared__ int rs[64];
    __shared__ int pos[64];
    int b = blockIdx.x, t = threadIdx.x;
    int s0 = b * CAP;
    int ne = gcur[b]; ne = (ne < CAP) ? ne : CAP;
    unsigned ev[4];
#pragma unroll
    for (int u = 0; u < 4; ++u) {
        int i = t + u * 256;
        ev[u] = (i < ne) ? ebuf[s0 + i] : 0xFFFFFFFFu;
    }
    if (t < 64) cnt[t] = 0;
    __syncthreads();
#pragma unroll
    for (int u = 0; u < 4; ++u)
        if (ev[u] != 0xFFFFFFFFu) atomicAdd(&cnt[ev[u] >> 17], 1);
    __syncthreads();
    if (t < 64) sd[t] = cnt[t];
    __syncthreads();
    for (int off = 1; off < 64; off <<= 1) {
        int u = (t >= off && t < 64) ? sd[t - off] : 0;
        __syncthreads();
        if (t < 64) sd[t] += u;
        __syncthreads();
    }
    if (t < 64) {
        int ex = sd[t] - cnt[t];
        rs[t] = ex;
        pos[t] = ex;
    }
    __syncthreads();
#pragma unroll
    for (int u = 0; u < 4; ++u) {
        if (ev[u] != 0xFFFFFFFFu) {
            int ld = (int)(ev[u] >> 17);
            int p = atomicAdd(&pos[ld], 1);
            csr_l[p] = (int)(ev[u] & 0x1FFFFu);
        }
    }
    // publish row metadata + global csr (for agg2)
    if (t < NPB) {
        int node = b * NPB + t;
        if (node < N) {
            rowstart[node] = s0 + rs[t];
            rowcnt[node] = cnt[t];
        }
    }
    __syncthreads();
    for (int i = t; i < ne; i += 256) csr[s0 + i] = csr_l[i];

    // ---- aggregate this bucket's nodes (node-per-wave, register accumulators) ----
    int w = t >> 6, lane = t & 63;
    int l = lane & 7, g = lane >> 3;
    for (int n = w; n < NPB; n += 4) {
        int node = b * NPB + n;
        if (node >= N) break;
        int beg = rs[n];
        int deg = cnt[n];
        float acc[8];
#pragma unroll
        for (int k = 0; k < 8; ++k) acc[k] = 0.f;
        int jmax = (deg + 7) >> 3;
        int full = jmax - 1;
        int j = 0;
        for (; j + 2 <= full; j += 2) {
            int s0e = csr_l[beg + j * 8 + g];
            int s1e = csr_l[beg + (j + 1) * 8 + g];
            uint4 v0 = *(const uint4*)(xh + (size_t)s0e * D0 + l * 8);
            uint4 v1 = *(const uint4*)(xh + (size_t)s1e * D0 + l * 8);
            acc[0] += __uint_as_float(v0.x << 16);  acc[1] += __uint_as_float(v0.x & 0xffff0000u);
            acc[2] += __uint_as_float(v0.y << 16);  acc[3] += __uint_as_float(v0.y & 0xffff0000u);
            acc[4] += __uint_as_float(v0.z << 16);  acc[5] += __uint_as_float(v0.z & 0xffff0000u);
            acc[6] += __uint_as_float(v0.w << 16);  acc[7] += __uint_as_float(v0.w & 0xffff0000u);
            acc[0] += __uint_as_float(v1.x << 16);  acc[1] += __uint_as_float(v1.x & 0xffff0000u);
            acc[2] += __uint_as_float(v1.y << 16);  acc[3] += __uint_as_float(v1.y & 0xffff0000u);
            acc[4] += __uint_as_float(v1.z << 16);  acc[5] += __uint_as_float(v1.z & 0xffff0000u);
            acc[6] += __uint_as_float(v1.w << 16);  acc[7] += __uint_as_float(v1.w & 0xffff0000u);
        }
        if (j < full) {
            int s0e = csr_l[beg + j * 8 + g];
            uint4 v0 = *(const uint4*)(xh + (size_t)s0e * D0 + l * 8);
            acc[0] += __uint_as_float(v0.x << 16);  acc[1] += __uint_as_float(v0.x & 0xffff0000u);
            acc[2] += __uint_as_float(v0.y << 16);  acc[3] += __uint_as_float(v0.y & 0xffff0000u);
            acc[4] += __uint_as_float(v0.z << 16);  acc[5] += __uint_as_float(v0.z & 0xffff0000u);
            acc[6] += __uint_as_float(v0.w << 16);  acc[7] += __uint_as_float(v0.w & 0xffff0000u);
        }
        if (jmax > 0) {
            int slot = full * 8 + g;
            int e = beg + ((slot < deg) ? slot : (deg - 1));
            int s0e = csr_l[e];
            float wgt = (slot < deg) ? 1.f : 0.f;
            uint4 v0 = *(const uint4*)(xh + (size_t)s0e * D0 + l * 8);
            acc[0] = fmaf(wgt, __uint_as_float(v0.x << 16), acc[0]);
            acc[1] = fmaf(wgt, __uint_as_float(v0.x & 0xffff0000u), acc[1]);
            acc[2] = fmaf(wgt, __uint_as_float(v0.y << 16), acc[2]);
            acc[3] = fmaf(wgt, __uint_as_float(v0.y & 0xffff0000u), acc[3]);
            acc[4] = fmaf(wgt, __uint_as_float(v0.z << 16), acc[4]);
            acc[5] = fmaf(wgt, __uint_as_float(v0.z & 0xffff0000u), acc[5]);
            acc[6] = fmaf(wgt, __uint_as_float(v0.w << 16), acc[6]);
            acc[7] = fmaf(wgt, __uint_as_float(v0.w & 0xffff0000u), acc[7]);
        }
#pragma unroll
        for (int off = 8; off <= 32; off <<= 1) {
#pragma unroll
            for (int k = 0; k < 8; ++k) acc[k] += __shfl_xor(acc[k], off);
        }
        float inv = 1.f / (float)max(deg, 1);
        if (g == 0) {
            unsigned o0 = (unsigned)f2bf(acc[0] * inv) | ((unsigned)f2bf(acc[1] * inv) << 16);
            unsigned o1 = (unsigned)f2bf(acc[2] * inv) | ((unsigned)f2bf(acc[3] * inv) << 16);
            unsigned o2 = (unsigned)f2bf(acc[4] * inv) | ((unsigned)f2bf(acc[5] * inv) << 16);
            unsigned o3 = (unsigned)f2bf(acc[6] * inv) | ((unsigned)f2bf(acc[7] * inv) << 16);
            uint4 pk; pk.x = o0; pk.y = o1; pk.z = o2; pk.w = o3;
            *(uint4*)(aggh + (size_t)node * D0 + l * 8) = pk;
        }
    }
}

// ---------------- agg2 + log_softmax: 5 lanes/edge x uint4, 12 edges/instr ----------------
// p2h rows padded to 64 shorts (128 B) -> every edge gather = exactly one cache line

__global__ void agg2_kernel(const unsigned short* __restrict__ p2h, const float* __restrict__ r2,
                            const int* __restrict__ rowstart, const int* __restrict__ rowcnt,
                            const int* __restrict__ csr,
                            float* __restrict__ out, float* __restrict__ out2, int N) {
    int wid = (blockIdx.x * blockDim.x + threadIdx.x) >> 6;
    int lane = threadIdx.x & 63;
    if (wid >= N) return;
    int beg = rowstart[wid];
    int deg = rowcnt[wid];
    int g = lane / 5;             // 0..12 (g==12: lanes 60..63 idle)
    int l = lane - g * 5;         // 0..4
    bool gv = g < 12;
    float a[8];
#pragma unroll
    for (int k = 0; k < 8; ++k) a[k] = 0.f;
    int jmax = (deg + 11) / 12;
    int full = jmax - 1;
    int j = 0;
    for (; j + 2 <= full; j += 2) {
        int s0 = csr[beg + j * 12 + g];
        int s1 = csr[beg + (j + 1) * 12 + g];
        uint4 v0 = *(const uint4*)(p2h + (size_t)s0 * 64 + l * 8);
        uint4 v1 = *(const uint4*)(p2h + (size_t)s1 * 64 + l * 8);
        if (gv) {
            a[0] += __uint_as_float(v0.x << 16);  a[1] += __uint_as_float(v0.x & 0xffff0000u);
            a[2] += __uint_as_float(v0.y << 16);  a[3] += __uint_as_float(v0.y & 0xffff0000u);
            a[4] += __uint_as_float(v0.z << 16);  a[5] += __uint_as_float(v0.z & 0xffff0000u);
            a[6] += __uint_as_float(v0.w << 16);  a[7] += __uint_as_float(v0.w & 0xffff0000u);
            a[0] += __uint_as_float(v1.x << 16);  a[1] += __uint_as_float(v1.x & 0xffff0000u);
            a[2] += __uint_as_float(v1.y << 16);  a[3] += __uint_as_float(v1.y & 0xffff0000u);
            a[4] += __uint_as_float(v1.z << 16);  a[5] += __uint_as_float(v1.z & 0xffff0000u);
            a[6] += __uint_as_float(v1.w << 16);  a[7] += __uint_as_float(v1.w & 0xffff0000u);
        }
    }
    if (j < full) {
        int s0 = csr[beg + j * 12 + g];
        uint4 v0 = *(const uint4*)(p2h + (size_t)s0 * 64 + l * 8);
        if (gv) {
            a[0] += __uint_as_float(v0.x << 16);  a[1] += __uint_as_float(v0.x & 0xffff0000u);
            a[2] += __uint_as_float(v0.y << 16);  a[3] += __uint_as_float(v0.y & 0xffff0000u);
            a[4] += __uint_as_float(v0.z << 16);  a[5] += __uint_as_float(v0.z & 0xffff0000u);
            a[6] += __uint_as_float(v0.w << 16);  a[7] += __uint_as_float(v0.w & 0xffff0000u);
        }
    }
    if (jmax > 0) {
        int slot = full * 12 + g;
        int e = beg + ((slot < deg) ? slot : (deg - 1));
        int s0 = csr[e];
        float w = (gv && slot < deg) ? 1.f : 0.f;
        uint4 v0 = *(const uint4*)(p2h + (size_t)s0 * 64 + l * 8);
        a[0] = fmaf(w, __uint_as_float(v0.x << 16), a[0]);
        a[1] = fmaf(w, __uint_as_float(v0.x & 0xffff0000u), a[1]);
        a[2] = fmaf(w, __uint_as_float(v0.y << 16), a[2]);
        a[3] = fmaf(w, __uint_as_float(v0.y & 0xffff0000u), a[3]);
        a[4] = fmaf(w, __uint_as_float(v0.z << 16), a[4]);
        a[5] = fmaf(w, __uint_as_float(v0.z & 0xffff0000u), a[5]);
        a[6] = fmaf(w, __uint_as_float(v0.w << 16), a[6]);
        a[7] = fmaf(w, __uint_as_float(v0.w & 0xffff0000u), a[7]);
    }
    {
        float b0;
#pragma unroll
        for (int k = 0; k < 8; ++k) { b0 = __shfl(a[k], lane + 30); if (g < 6) a[k] += b0; }
#pragma unroll
        for (int k = 0; k < 8; ++k) { b0 = __shfl(a[k], lane + 15); if (g < 3) a[k] += b0; }
#pragma unroll
        for (int k = 0; k < 8; ++k) {
            float c1 = __shfl(a[k], lane + 5);
            float c2 = __shfl(a[k], lane + 10);
            if (g == 0) a[k] += c1 + c2;
        }
    }
    float inv = 1.f / (float)max(deg, 1);
    bool wr = (lane < 5);
    float h2[8];
    if (wr) {
        float4 ra = *(const float4*)(r2 + (size_t)wid * D2 + lane * 8);
        float4 rb = *(const float4*)(r2 + (size_t)wid * D2 + lane * 8 + 4);
        h2[0] = ra.x + a[0] * inv; h2[1] = ra.y + a[1] * inv;
        h2[2] = ra.z + a[2] * inv; h2[3] = ra.w + a[3] * inv;
        h2[4] = rb.x + a[4] * inv; h2[5] = rb.y + a[5] * inv;
        h2[6] = rb.z + a[6] * inv; h2[7] = rb.w + a[7] * inv;
        float4 oa; oa.x = h2[0]; oa.y = h2[1]; oa.z = h2[2]; oa.w = h2[3];
        float4 ob; ob.x = h2[4]; ob.y = h2[5]; ob.z = h2[6]; ob.w = h2[7];
        *(float4*)(out + (size_t)wid * D2 + lane * 8) = oa;
        *(float4*)(out + (size_t)wid * D2 + lane * 8 + 4) = ob;
    }
    float m = -INFINITY;
    if (wr) {
#pragma unroll
        for (int k = 0; k < 8; ++k) m = fmaxf(m, h2[k]);
    }
#pragma unroll
    for (int off = 1; off < 64; off <<= 1) m = fmaxf(m, __shfl_xor(m, off));
    float s = 0.f;
    if (wr) {
#pragma unroll
        for (int k = 0; k < 8; ++k) s += expf(h2[k] - m);
    }
#pragma unroll
    for (int off = 1; off < 64; off <<= 1) s += __shfl_xor(s, off);
    if (wr) {
        float lg = m + logf(s);
        float4 oa; oa.x = h2[0] - lg; oa.y = h2[1] - lg; oa.z = h2[2] - lg; oa.w = h2[3] - lg;
        float4 ob; ob.x = h2[4] - lg; ob.y = h2[5] - lg; ob.z = h2[6] - lg; ob.w = h2[7] - lg;
        *(float4*)(out2 + (size_t)wid * D2 + lane * 8) = oa;
        *(float4*)(out2 + (size_t)wid * D2 + lane * 8 + 4) = ob;
    }
}

// ---------------- fused GEMM (64-row tiles): h=relu([x|agg]@[W1r;W1l]+b1) staged in LDS,
//                  then p2h(bf16,stride64)=h@W2l ; r2(f32)=h@W2r+b2 ----------------
// Each wave owns LDS rows [w*16, w*16+16) exclusively after the initial barrier.
__global__ __launch_bounds__(256) void gemm_fused(
        const unsigned short* __restrict__ xh, const unsigned short* __restrict__ aggh,
        const unsigned short* __restrict__ Wpk1, const unsigned short* __restrict__ Wpk2,
        const float* __restrict__ b1, const float* __restrict__ b2,
        unsigned short* __restrict__ p2h, float* __restrict__ r2, int N) {
    __shared__ __align__(16) unsigned short As[64 * 136];  // [row][k], +8 pad
    int t = threadIdx.x;
    int r0 = blockIdx.x * 64;
    for (int i = t; i < 1024; i += 256) {
        int r = i >> 4, c = i & 15;
        int gr = r0 + r; gr = (gr < N) ? gr : (N - 1);
        uint4 v = (c < 8) ? ((const uint4*)(xh + (size_t)gr * 64))[c]
                          : ((const uint4*)(aggh + (size_t)gr * 64))[c - 8];
        *(uint4*)(As + r * 136 + c * 8) = v;
    }
    __syncthreads();
    int w = t >> 6, lane = t & 63;
    int l15 = lane & 15, q = lane >> 4;
    f32x4 zero = {0.f, 0.f, 0.f, 0.f};
    const unsigned short* abase = As + (w * 16 + l15) * 136 + q * 8;

    f32x4 acc[8];
#pragma unroll
    for (int nt = 0; nt < 8; ++nt) acc[nt] = zero;
#pragma unroll
    for (int ks = 0; ks < 4; ++ks) {
        s16x8 a0 = *(const s16x8*)(abase + ks * 32);
        s16x8 b[8];
#pragma unroll
        for (int nt = 0; nt < 8; ++nt)
            b[nt] = *(const s16x8*)(Wpk1 + ((size_t)(ks * 8 + nt) * 64 + lane) * 8);
#pragma unroll
        for (int nt = 0; nt < 8; ++nt)
            acc[nt] = __builtin_amdgcn_mfma_f32_16x16x32_bf16(a0, b[nt], acc[nt], 0, 0, 0);
    }
    int rloc = w * 16 + q * 4;
#pragma unroll
    for (int nt = 0; nt < 8; ++nt) {
        int col = nt * 16 + l15;
        float bias = b1[col];
#pragma unroll
        for (int reg = 0; reg < 4; ++reg)
            As[(rloc + reg) * 136 + col] = f2bf(fmaxf(acc[nt][reg] + bias, 0.f));
    }
    f32x4 acc2[5];
#pragma unroll
    for (int nt = 0; nt < 5; ++nt) acc2[nt] = zero;
#pragma unroll
    for (int ks = 0; ks < 4; ++ks) {
        s16x8 a0 = *(const s16x8*)(abase + ks * 32);
        s16x8 b[5];
#pragma unroll
        for (int nt = 0; nt < 5; ++nt)
            b[nt] = *(const s16x8*)(Wpk2 + ((size_t)(ks * 5 + nt) * 64 + lane) * 8);
#pragma unroll
        for (int nt = 0; nt < 5; ++nt)
            acc2[nt] = __builtin_amdgcn_mfma_f32_16x16x32_bf16(a0, b[nt], acc2[nt], 0, 0, 0);
    }
    int rbase = r0 + w * 16 + q * 4;
#pragma unroll
    for (int nt = 0; nt < 5; ++nt) {
        int col = nt * 16 + l15;   // 0..79
        bool isp = col < 40;
        int oc = isp ? col : (col - 40);
        float bias = isp ? 0.f : b2[oc];
#pragma unroll
        for (int reg = 0; reg < 4; ++reg) {
            int row = rbase + reg;
            if (row < N) {
                float v = acc2[nt][reg] + bias;
                if (isp) p2h[(size_t)row * 64 + oc] = f2bf(v);
                else     r2[(size_t)row * D2 + oc] = v;
            }
        }
    }
}

// ---------------- launch ----------------

extern "C" void kernel_launch(void* const* d_in, const int* in_sizes, int n_in,
                              void* d_out, int out_size, void* d_ws, size_t ws_size,
                              hipStream_t stream) {
    const float* x   = (const float*)d_in[0];
    const int*   ei  = (const int*)d_in[1];
    const float* W1l = (const float*)d_in[2];
    const float* W1r = (const float*)d_in[3];
    const float* b1  = (const float*)d_in[4];
    const float* W2l = (const float*)d_in[5];
    const float* W2r = (const float*)d_in[6];
    const float* b2  = (const float*)d_in[7];
    float* out = (float*)d_out;

    const int N = N_NODES;
    const int E = in_sizes[1] / 2;
    const int* src = ei;
    const int* dst = ei + E;

    char* p = (char*)d_ws;
    auto alloc = [&](size_t bytes) -> void* {
        void* r = (void*)p;
        p += (bytes + 255) & ~(size_t)255;
        return r;
    };
    const int nScat = (E + 4095) / 4096;           // 196
    const int nCast = (N * D0) / 1024;             // 3125 (exact)

    unsigned* ebuf     = (unsigned*)alloc((size_t)NB * CAP * 4);   // 4 MB
    int*      csr      = (int*)alloc((size_t)NB * CAP * 4);        // 4 MB
    int*      gcur     = (int*)alloc(NB * 4);
    int*      rowstart = (int*)alloc((size_t)N * 4);
    int*      rowcnt   = (int*)alloc((size_t)N * 4);
    unsigned short* xh    = (unsigned short*)alloc((size_t)N * D0 * 2);
    unsigned short* aggh  = (unsigned short*)alloc((size_t)N * D0 * 2);
    unsigned short* wpk1  = (unsigned short*)alloc((size_t)32 * 64 * 8 * 2);
    unsigned short* wpk2  = (unsigned short*)alloc((size_t)20 * 64 * 8 * 2);
    unsigned short* p2h   = (unsigned short*)alloc((size_t)N * 64 * 2);   // 128 B stride
    float* r2buf = (float*)alloc((size_t)N * D2 * 4);

    // zero bucket cursors, then fused prep (LDS-aggregated scatter + cast + pack)
    hipMemsetAsync(gcur, 0, NB * sizeof(int), stream);
    prep_scatter_kernel<<<nScat + nCast + 8 + 5, 256, 0, stream>>>(
        x, src, dst, W1l, W1r, W2l, W2r, xh, gcur, ebuf, wpk1, wpk2, E, nScat, nCast);

    // fused per-bucket fill + layer-1 aggregation
    fillagg1_kernel<<<NB, 256, 0, stream>>>(xh, ebuf, gcur, rowstart, rowcnt, csr, aggh, N);

    // fused GEMM1+ReLU+GEMM2 (64-row tiles)
    gemm_fused<<<(N + 63) / 64, 256, 0, stream>>>(xh, aggh, wpk1, wpk2, b1, b2,
                                                  p2h, r2buf, N);

    // layer-2 aggregation of projected features + fused log_softmax
    agg2_kernel<<<(N * 64 + 255) / 256, 256, 0, stream>>>(p2h, r2buf, rowstart, rowcnt, csr,
                                                          out, out + (size_t)N * D2, N);
}

// Round 7
// 168.887 us; speedup vs baseline: 3.2894x; 1.0042x over previous
//
#include <hip/hip_runtime.h>
#include <hip/hip_bf16.h>
#include <math.h>

#define N_NODES 50000
#define D0 64
#define D1 128
#define D2 40

#define NB  784   // buckets; one bucket == one 64-row GEMM tile (784*64 = 50176 >= 50000)
#define NPB 64    // nodes per bucket
#define CAP 1280  // per-bucket edge capacity (mean 1020, +8.1 sigma)

typedef short s16x8 __attribute__((ext_vector_type(8)));
typedef float f32x4 __attribute__((ext_vector_type(4)));

static __device__ __forceinline__ unsigned short f2bf(float v) {
    __hip_bfloat16 hb = __float2bfloat16(v);
    return *(unsigned short*)&hb;
}

// ---------------- fused prep: LDS-aggregated bucket scatter + cast x + pack weights --------
__global__ __launch_bounds__(256) void prep_scatter_kernel(
        const float* __restrict__ x, const int* __restrict__ src, const int* __restrict__ dst,
        const float* __restrict__ W1l, const float* __restrict__ W1r,
        const float* __restrict__ W2l, const float* __restrict__ W2r,
        unsigned short* __restrict__ xh, int* __restrict__ gcur, unsigned* __restrict__ ebuf,
        unsigned short* __restrict__ wpk1, unsigned short* __restrict__ wpk2,
        int E, int nScat, int nCast) {
    int b = blockIdx.x, t = threadIdx.x;
    if (b < nScat) {
        __shared__ int h[NB];
        __shared__ int base[NB];
        int e0 = b * 4096;
        for (int i = t; i < NB; i += 256) h[i] = 0;
        __syncthreads();
        int dloc[16];
#pragma unroll
        for (int u = 0; u < 16; ++u) {
            int e = e0 + u * 256 + t;
            dloc[u] = (e < E) ? dst[e] : -1;
            if (dloc[u] >= 0) atomicAdd(&h[(unsigned)dloc[u] >> 6], 1);
        }
        __syncthreads();
        for (int u = t; u < NB; u += 256)
            if (h[u] > 0) base[u] = u * CAP + atomicAdd(&gcur[u], h[u]);
        __syncthreads();
        for (int i = t; i < NB; i += 256) h[i] = 0;
        __syncthreads();
#pragma unroll
        for (int u = 0; u < 16; ++u) {
            int e = e0 + u * 256 + t;
            if (dloc[u] >= 0) {
                unsigned d = (unsigned)dloc[u];
                unsigned bk = d >> 6;
                unsigned ld = d & 63u;
                int k = atomicAdd(&h[bk], 1);
                ebuf[base[bk] + k] = (ld << 17) | (unsigned)src[e];
            }
        }
    } else if (b < nScat + nCast) {
        int i = ((b - nScat) * 256 + t) * 4;   // nCast*1024 == N*D0 exactly
        float4 v = *(const float4*)(x + i);
        unsigned o0 = (unsigned)f2bf(v.x) | ((unsigned)f2bf(v.y) << 16);
        unsigned o1 = (unsigned)f2bf(v.z) | ((unsigned)f2bf(v.w) << 16);
        uint2 pk; pk.x = o0; pk.y = o1;
        *(uint2*)(xh + i) = pk;
    } else if (b < nScat + nCast + 8) {
        int f = (b - nScat - nCast) * 4 + (t >> 6);   // 0..31
        int lane = t & 63;
        int nt = f & 7;
        int col = nt * 16 + (lane & 15);
        int kbase = (f >> 3) * 32 + (lane >> 4) * 8;
        unsigned short* o = wpk1 + ((size_t)f * 64 + lane) * 8;
#pragma unroll
        for (int j = 0; j < 8; ++j) {
            int k = kbase + j;
            float w = (k < 64) ? W1r[k * 128 + col] : W1l[(k - 64) * 128 + col];
            o[j] = f2bf(w);
        }
    } else {
        int f = (b - nScat - nCast - 8) * 4 + (t >> 6);   // 0..19
        if (f < 20) {
            int lane = t & 63;
            int nt = f % 5;
            int col = nt * 16 + (lane & 15);       // 0..79
            int kbase = (f / 5) * 32 + (lane >> 4) * 8;
            unsigned short* o = wpk2 + ((size_t)f * 64 + lane) * 8;
#pragma unroll
            for (int j = 0; j < 8; ++j) {
                int k = kbase + j;
                float w = (col < 40) ? W2l[k * 40 + col] : W2r[k * 40 + (col - 40)];
                o[j] = f2bf(w);
            }
        }
    }
}

// ---------------- fused fill + agg1 + GEMM1 + ReLU + GEMM2 ----------------
// One block per bucket == one 64-row tile. LDS counting-sort -> local CSR; node-per-wave
// aggregation with register accumulators writes the bf16 mean straight into the A-tile
// (cols 64..127) next to the staged xh rows (cols 0..63); then both MFMA phases in place.
__global__ __launch_bounds__(256) void fillagg1gemm_kernel(
        const unsigned short* __restrict__ xh, const unsigned* __restrict__ ebuf,
        const int* __restrict__ gcur,
        const unsigned short* __restrict__ Wpk1, const unsigned short* __restrict__ Wpk2,
        const float* __restrict__ b1, const float* __restrict__ b2,
        int* __restrict__ rowstart, int* __restrict__ rowcnt, int* __restrict__ csr,
        unsigned short* __restrict__ p2h, float* __restrict__ r2, int N) {
    __shared__ int csr_l[CAP];
    __shared__ int cnt[64];
    __shared__ int sd[64];
    __shared__ int rs[64];
    __shared__ int pos[64];
    __shared__ __align__(16) unsigned short As[64 * 136];  // [row][k], +8 pad
    int b = blockIdx.x, t = threadIdx.x;
    int r0 = b * 64;
    // stage xh rows into As[:, 0:64] (coalesced 8 KB)
    for (int i = t; i < 512; i += 256) {
        int r = i >> 3, c = i & 7;
        int gr = r0 + r; gr = (gr < N) ? gr : (N - 1);
        *(uint4*)(As + r * 136 + c * 8) = ((const uint4*)(xh + (size_t)gr * 64))[c];
    }
    int s0 = b * CAP;
    int ne = gcur[b]; ne = (ne < CAP) ? ne : CAP;
    unsigned ev[5];
#pragma unroll
    for (int u = 0; u < 5; ++u) {
        int i = t + u * 256;
        ev[u] = (i < ne) ? ebuf[s0 + i] : 0xFFFFFFFFu;
    }
    if (t < 64) cnt[t] = 0;
    __syncthreads();
#pragma unroll
    for (int u = 0; u < 5; ++u)
        if (ev[u] != 0xFFFFFFFFu) atomicAdd(&cnt[ev[u] >> 17], 1);
    __syncthreads();
    if (t < 64) sd[t] = cnt[t];
    __syncthreads();
    for (int off = 1; off < 64; off <<= 1) {
        int u = (t >= off && t < 64) ? sd[t - off] : 0;
        __syncthreads();
        if (t < 64) sd[t] += u;
        __syncthreads();
    }
    if (t < 64) {
        int ex = sd[t] - cnt[t];
        rs[t] = ex;
        pos[t] = ex;
    }
    __syncthreads();
#pragma unroll
    for (int u = 0; u < 5; ++u) {
        if (ev[u] != 0xFFFFFFFFu) {
            int ld = (int)(ev[u] >> 17);
            int p = atomicAdd(&pos[ld], 1);
            csr_l[p] = (int)(ev[u] & 0x1FFFFu);
        }
    }
    if (t < 64) {
        int node = r0 + t;
        if (node < N) {
            rowstart[node] = s0 + rs[t];
            rowcnt[node] = cnt[t];
        }
    }
    __syncthreads();
    for (int i = t; i < ne; i += 256) csr[s0 + i] = csr_l[i];

    // ---- aggregate this bucket's 64 nodes (node-per-wave, register accumulators) ----
    int w = t >> 6, lane = t & 63;
    int l = lane & 7, g = lane >> 3;
    for (int n = w; n < 64; n += 4) {
        int node = r0 + n;
        if (node >= N) break;
        int beg = rs[n];
        int deg = cnt[n];
        float acc[8];
#pragma unroll
        for (int k = 0; k < 8; ++k) acc[k] = 0.f;
        int jmax = (deg + 7) >> 3;
        int full = jmax - 1;
        int j = 0;
        for (; j + 2 <= full; j += 2) {
            int s0e = csr_l[beg + j * 8 + g];
            int s1e = csr_l[beg + (j + 1) * 8 + g];
            uint4 v0 = *(const uint4*)(xh + (size_t)s0e * D0 + l * 8);
            uint4 v1 = *(const uint4*)(xh + (size_t)s1e * D0 + l * 8);
            acc[0] += __uint_as_float(v0.x << 16);  acc[1] += __uint_as_float(v0.x & 0xffff0000u);
            acc[2] += __uint_as_float(v0.y << 16);  acc[3] += __uint_as_float(v0.y & 0xffff0000u);
            acc[4] += __uint_as_float(v0.z << 16);  acc[5] += __uint_as_float(v0.z & 0xffff0000u);
            acc[6] += __uint_as_float(v0.w << 16);  acc[7] += __uint_as_float(v0.w & 0xffff0000u);
            acc[0] += __uint_as_float(v1.x << 16);  acc[1] += __uint_as_float(v1.x & 0xffff0000u);
            acc[2] += __uint_as_float(v1.y << 16);  acc[3] += __uint_as_float(v1.y & 0xffff0000u);
            acc[4] += __uint_as_float(v1.z << 16);  acc[5] += __uint_as_float(v1.z & 0xffff0000u);
            acc[6] += __uint_as_float(v1.w << 16);  acc[7] += __uint_as_float(v1.w & 0xffff0000u);
        }
        if (j < full) {
            int s0e = csr_l[beg + j * 8 + g];
            uint4 v0 = *(const uint4*)(xh + (size_t)s0e * D0 + l * 8);
            acc[0] += __uint_as_float(v0.x << 16);  acc[1] += __uint_as_float(v0.x & 0xffff0000u);
            acc[2] += __uint_as_float(v0.y << 16);  acc[3] += __uint_as_float(v0.y & 0xffff0000u);
            acc[4] += __uint_as_float(v0.z << 16);  acc[5] += __uint_as_float(v0.z & 0xffff0000u);
            acc[6] += __uint_as_float(v0.w << 16);  acc[7] += __uint_as_float(v0.w & 0xffff0000u);
        }
        if (jmax > 0) {
            int slot = full * 8 + g;
            int e = beg + ((slot < deg) ? slot : (deg - 1));
            int s0e = csr_l[e];
            float wgt = (slot < deg) ? 1.f : 0.f;
            uint4 v0 = *(const uint4*)(xh + (size_t)s0e * D0 + l * 8);
            acc[0] = fmaf(wgt, __uint_as_float(v0.x << 16), acc[0]);
            acc[1] = fmaf(wgt, __uint_as_float(v0.x & 0xffff0000u), acc[1]);
            acc[2] = fmaf(wgt, __uint_as_float(v0.y << 16), acc[2]);
            acc[3] = fmaf(wgt, __uint_as_float(v0.y & 0xffff0000u), acc[3]);
            acc[4] = fmaf(wgt, __uint_as_float(v0.z << 16), acc[4]);
            acc[5] = fmaf(wgt, __uint_as_float(v0.z & 0xffff0000u), acc[5]);
            acc[6] = fmaf(wgt, __uint_as_float(v0.w << 16), acc[6]);
            acc[7] = fmaf(wgt, __uint_as_float(v0.w & 0xffff0000u), acc[7]);
        }
#pragma unroll
        for (int off = 8; off <= 32; off <<= 1) {
#pragma unroll
            for (int k = 0; k < 8; ++k) acc[k] += __shfl_xor(acc[k], off);
        }
        float inv = 1.f / (float)max(deg, 1);
        if (g == 0) {   // write bf16 mean straight into A-tile cols 64..127
            unsigned o0 = (unsigned)f2bf(acc[0] * inv) | ((unsigned)f2bf(acc[1] * inv) << 16);
            unsigned o1 = (unsigned)f2bf(acc[2] * inv) | ((unsigned)f2bf(acc[3] * inv) << 16);
            unsigned o2 = (unsigned)f2bf(acc[4] * inv) | ((unsigned)f2bf(acc[5] * inv) << 16);
            unsigned o3 = (unsigned)f2bf(acc[6] * inv) | ((unsigned)f2bf(acc[7] * inv) << 16);
            uint4 pk; pk.x = o0; pk.y = o1; pk.z = o2; pk.w = o3;
            *(uint4*)(As + n * 136 + 64 + l * 8) = pk;
        }
    }
    __syncthreads();

    // ---- GEMM phase 1: [x|agg] @ [W1r;W1l] ----
    int l15 = lane & 15, q = lane >> 4;
    f32x4 zero = {0.f, 0.f, 0.f, 0.f};
    const unsigned short* abase = As + (w * 16 + l15) * 136 + q * 8;
    f32x4 acc1[8];
#pragma unroll
    for (int nt = 0; nt < 8; ++nt) acc1[nt] = zero;
#pragma unroll
    for (int ks = 0; ks < 4; ++ks) {
        s16x8 a0 = *(const s16x8*)(abase + ks * 32);
        s16x8 bb[8];
#pragma unroll
        for (int nt = 0; nt < 8; ++nt)
            bb[nt] = *(const s16x8*)(Wpk1 + ((size_t)(ks * 8 + nt) * 64 + lane) * 8);
#pragma unroll
        for (int nt = 0; nt < 8; ++nt)
            acc1[nt] = __builtin_amdgcn_mfma_f32_16x16x32_bf16(a0, bb[nt], acc1[nt], 0, 0, 0);
    }
    // stage h = relu(acc + b1) back into wave-private rows (in-wave LDS ordering suffices)
    int rloc = w * 16 + q * 4;
#pragma unroll
    for (int nt = 0; nt < 8; ++nt) {
        int col = nt * 16 + l15;
        float bias = b1[col];
#pragma unroll
        for (int reg = 0; reg < 4; ++reg)
            As[(rloc + reg) * 136 + col] = f2bf(fmaxf(acc1[nt][reg] + bias, 0.f));
    }
    // ---- GEMM phase 2: h @ [W2l|W2r] ----
    f32x4 acc2[5];
#pragma unroll
    for (int nt = 0; nt < 5; ++nt) acc2[nt] = zero;
#pragma unroll
    for (int ks = 0; ks < 4; ++ks) {
        s16x8 a0 = *(const s16x8*)(abase + ks * 32);
        s16x8 bb[5];
#pragma unroll
        for (int nt = 0; nt < 5; ++nt)
            bb[nt] = *(const s16x8*)(Wpk2 + ((size_t)(ks * 5 + nt) * 64 + lane) * 8);
#pragma unroll
        for (int nt = 0; nt < 5; ++nt)
            acc2[nt] = __builtin_amdgcn_mfma_f32_16x16x32_bf16(a0, bb[nt], acc2[nt], 0, 0, 0);
    }
    int rbase = r0 + w * 16 + q * 4;
#pragma unroll
    for (int nt = 0; nt < 5; ++nt) {
        int col = nt * 16 + l15;   // 0..79
        bool isp = col < 40;
        int oc = isp ? col : (col - 40);
        float bias = isp ? 0.f : b2[oc];
#pragma unroll
        for (int reg = 0; reg < 4; ++reg) {
            int row = rbase + reg;
            if (row < N) {
                float v = acc2[nt][reg] + bias;
                if (isp) p2h[(size_t)row * 64 + oc] = f2bf(v);
                else     r2[(size_t)row * D2 + oc] = v;
            }
        }
    }
}

// ---------------- agg2 + log_softmax: 5 lanes/edge x uint4, 12 edges/instr ----------------
// p2h rows padded to 64 shorts (128 B) -> every edge gather = exactly one cache line

__global__ void agg2_kernel(const unsigned short* __restrict__ p2h, const float* __restrict__ r2,
                            const int* __restrict__ rowstart, const int* __restrict__ rowcnt,
                            const int* __restrict__ csr,
                            float* __restrict__ out, float* __restrict__ out2, int N) {
    int wid = (blockIdx.x * blockDim.x + threadIdx.x) >> 6;
    int lane = threadIdx.x & 63;
    if (wid >= N) return;
    int beg = rowstart[wid];
    int deg = rowcnt[wid];
    int g = lane / 5;             // 0..12 (g==12: lanes 60..63 idle)
    int l = lane - g * 5;         // 0..4
    bool gv = g < 12;
    float a[8];
#pragma unroll
    for (int k = 0; k < 8; ++k) a[k] = 0.f;
    int jmax = (deg + 11) / 12;
    int full = jmax - 1;
    int j = 0;
    for (; j + 2 <= full; j += 2) {
        int s0 = csr[beg + j * 12 + g];
        int s1 = csr[beg + (j + 1) * 12 + g];
        uint4 v0 = *(const uint4*)(p2h + (size_t)s0 * 64 + l * 8);
        uint4 v1 = *(const uint4*)(p2h + (size_t)s1 * 64 + l * 8);
        if (gv) {
            a[0] += __uint_as_float(v0.x << 16);  a[1] += __uint_as_float(v0.x & 0xffff0000u);
            a[2] += __uint_as_float(v0.y << 16);  a[3] += __uint_as_float(v0.y & 0xffff0000u);
            a[4] += __uint_as_float(v0.z << 16);  a[5] += __uint_as_float(v0.z & 0xffff0000u);
            a[6] += __uint_as_float(v0.w << 16);  a[7] += __uint_as_float(v0.w & 0xffff0000u);
            a[0] += __uint_as_float(v1.x << 16);  a[1] += __uint_as_float(v1.x & 0xffff0000u);
            a[2] += __uint_as_float(v1.y << 16);  a[3] += __uint_as_float(v1.y & 0xffff0000u);
            a[4] += __uint_as_float(v1.z << 16);  a[5] += __uint_as_float(v1.z & 0xffff0000u);
            a[6] += __uint_as_float(v1.w << 16);  a[7] += __uint_as_float(v1.w & 0xffff0000u);
        }
    }
    if (j < full) {
        int s0 = csr[beg + j * 12 + g];
        uint4 v0 = *(const uint4*)(p2h + (size_t)s0 * 64 + l * 8);
        if (gv) {
            a[0] += __uint_as_float(v0.x << 16);  a[1] += __uint_as_float(v0.x & 0xffff0000u);
            a[2] += __uint_as_float(v0.y << 16);  a[3] += __uint_as_float(v0.y & 0xffff0000u);
            a[4] += __uint_as_float(v0.z << 16);  a[5] += __uint_as_float(v0.z & 0xffff0000u);
            a[6] += __uint_as_float(v0.w << 16);  a[7] += __uint_as_float(v0.w & 0xffff0000u);
        }
    }
    if (jmax > 0) {
        int slot = full * 12 + g;
        int e = beg + ((slot < deg) ? slot : (deg - 1));
        int s0 = csr[e];
        float w = (gv && slot < deg) ? 1.f : 0.f;
        uint4 v0 = *(const uint4*)(p2h + (size_t)s0 * 64 + l * 8);
        a[0] = fmaf(w, __uint_as_float(v0.x << 16), a[0]);
        a[1] = fmaf(w, __uint_as_float(v0.x & 0xffff0000u), a[1]);
        a[2] = fmaf(w, __uint_as_float(v0.y << 16), a[2]);
        a[3] = fmaf(w, __uint_as_float(v0.y & 0xffff0000u), a[3]);
        a[4] = fmaf(w, __uint_as_float(v0.z << 16), a[4]);
        a[5] = fmaf(w, __uint_as_float(v0.z & 0xffff0000u), a[5]);
        a[6] = fmaf(w, __uint_as_float(v0.w << 16), a[6]);
        a[7] = fmaf(w, __uint_as_float(v0.w & 0xffff0000u), a[7]);
    }
    {
        float b0;
#pragma unroll
        for (int k = 0; k < 8; ++k) { b0 = __shfl(a[k], lane + 30); if (g < 6) a[k] += b0; }
#pragma unroll
        for (int k = 0; k < 8; ++k) { b0 = __shfl(a[k], lane + 15); if (g < 3) a[k] += b0; }
#pragma unroll
        for (int k = 0; k < 8; ++k) {
            float c1 = __shfl(a[k], lane + 5);
            float c2 = __shfl(a[k], lane + 10);
            if (g == 0) a[k] += c1 + c2;
        }
    }
    float inv = 1.f / (float)max(deg, 1);
    bool wr = (lane < 5);
    float h2[8];
    if (wr) {
        float4 ra = *(const float4*)(r2 + (size_t)wid * D2 + lane * 8);
        float4 rb = *(const float4*)(r2 + (size_t)wid * D2 + lane * 8 + 4);
        h2[0] = ra.x + a[0] * inv; h2[1] = ra.y + a[1] * inv;
        h2[2] = ra.z + a[2] * inv; h2[3] = ra.w + a[3] * inv;
        h2[4] = rb.x + a[4] * inv; h2[5] = rb.y + a[5] * inv;
        h2[6] = rb.z + a[6] * inv; h2[7] = rb.w + a[7] * inv;
        float4 oa; oa.x = h2[0]; oa.y = h2[1]; oa.z = h2[2]; oa.w = h2[3];
        float4 ob; ob.x = h2[4]; ob.y = h2[5]; ob.z = h2[6]; ob.w = h2[7];
        *(float4*)(out + (size_t)wid * D2 + lane * 8) = oa;
        *(float4*)(out + (size_t)wid * D2 + lane * 8 + 4) = ob;
    }
    float m = -INFINITY;
    if (wr) {
#pragma unroll
        for (int k = 0; k < 8; ++k) m = fmaxf(m, h2[k]);
    }
#pragma unroll
    for (int off = 1; off < 64; off <<= 1) m = fmaxf(m, __shfl_xor(m, off));
    float s = 0.f;
    if (wr) {
#pragma unroll
        for (int k = 0; k < 8; ++k) s += expf(h2[k] - m);
    }
#pragma unroll
    for (int off = 1; off < 64; off <<= 1) s += __shfl_xor(s, off);
    if (wr) {
        float lg = m + logf(s);
        float4 oa; oa.x = h2[0] - lg; oa.y = h2[1] - lg; oa.z = h2[2] - lg; oa.w = h2[3] - lg;
        float4 ob; ob.x = h2[4] - lg; ob.y = h2[5] - lg; ob.z = h2[6] - lg; ob.w = h2[7] - lg;
        *(float4*)(out2 + (size_t)wid * D2 + lane * 8) = oa;
        *(float4*)(out2 + (size_t)wid * D2 + lane * 8 + 4) = ob;
    }
}

// ---------------- launch ----------------

extern "C" void kernel_launch(void* const* d_in, const int* in_sizes, int n_in,
                              void* d_out, int out_size, void* d_ws, size_t ws_size,
                              hipStream_t stream) {
    const float* x   = (const float*)d_in[0];
    const int*   ei  = (const int*)d_in[1];
    const float* W1l = (const float*)d_in[2];
    const float* W1r = (const float*)d_in[3];
    const float* b1  = (const float*)d_in[4];
    const float* W2l = (const float*)d_in[5];
    const float* W2r = (const float*)d_in[6];
    const float* b2  = (const float*)d_in[7];
    float* out = (float*)d_out;

    const int N = N_NODES;
    const int E = in_sizes[1] / 2;
    const int* src = ei;
    const int* dst = ei + E;

    char* p = (char*)d_ws;
    auto alloc = [&](size_t bytes) -> void* {
        void* r = (void*)p;
        p += (bytes + 255) & ~(size_t)255;
        return r;
    };
    const int nScat = (E + 4095) / 4096;           // 196
    const int nCast = (N * D0) / 1024;             // 3125 (exact)

    unsigned* ebuf     = (unsigned*)alloc((size_t)NB * CAP * 4);   // ~4 MB
    int*      csr      = (int*)alloc((size_t)NB * CAP * 4);        // ~4 MB
    int*      gcur     = (int*)alloc(NB * 4);
    int*      rowstart = (int*)alloc((size_t)N * 4);
    int*      rowcnt   = (int*)alloc((size_t)N * 4);
    unsigned short* xh    = (unsigned short*)alloc((size_t)N * D0 * 2);
    unsigned short* wpk1  = (unsigned short*)alloc((size_t)32 * 64 * 8 * 2);
    unsigned short* wpk2  = (unsigned short*)alloc((size_t)20 * 64 * 8 * 2);
    unsigned short* p2h   = (unsigned short*)alloc((size_t)N * 64 * 2);   // 128 B stride
    float* r2buf = (float*)alloc((size_t)N * D2 * 4);

    // zero bucket cursors, then fused prep (LDS-aggregated scatter + cast + pack)
    hipMemsetAsync(gcur, 0, NB * sizeof(int), stream);
    prep_scatter_kernel<<<nScat + nCast + 8 + 5, 256, 0, stream>>>(
        x, src, dst, W1l, W1r, W2l, W2r, xh, gcur, ebuf, wpk1, wpk2, E, nScat, nCast);

    // fused per-bucket fill + layer-1 aggregation + GEMM1 + ReLU + GEMM2 (one tile/block)
    fillagg1gemm_kernel<<<NB, 256, 0, stream>>>(xh, ebuf, gcur, wpk1, wpk2, b1, b2,
                                                rowstart, rowcnt, csr, p2h, r2buf, N);

    // layer-2 aggregation of projected features + fused log_softmax
    agg2_kernel<<<(N * 64 + 255) / 256, 256, 0, stream>>>(p2h, r2buf, rowstart, rowcnt, csr,
                                                          out, out + (size_t)N * D2, N);
}

// Round 8
// 162.962 us; speedup vs baseline: 3.4090x; 1.0364x over previous
//
#include <hip/hip_runtime.h>
#include <hip/hip_bf16.h>
#include <math.h>

#define N_NODES 50000
#define D0 64
#define D1 128
#define D2 40

#define NB  784   // buckets; one bucket == one 64-row GEMM tile (784*64 = 50176 >= 50000)
#define NPB 64    // nodes per bucket
#define CAP 1280  // per-bucket edge capacity (mean 1020, +8.1 sigma)

typedef short s16x8 __attribute__((ext_vector_type(8)));
typedef float f32x4 __attribute__((ext_vector_type(4)));

static __device__ __forceinline__ unsigned short f2bf(float v) {
    __hip_bfloat16 hb = __float2bfloat16(v);
    return *(unsigned short*)&hb;
}

// ---------------- fused prep: LDS-aggregated bucket scatter + cast x + pack weights --------
__global__ __launch_bounds__(256) void prep_scatter_kernel(
        const float* __restrict__ x, const int* __restrict__ src, const int* __restrict__ dst,
        const float* __restrict__ W1l, const float* __restrict__ W1r,
        const float* __restrict__ W2l, const float* __restrict__ W2r,
        unsigned short* __restrict__ xh, int* __restrict__ gcur, unsigned* __restrict__ ebuf,
        unsigned short* __restrict__ wpk1, unsigned short* __restrict__ wpk2,
        int E, int nScat, int nCast) {
    int b = blockIdx.x, t = threadIdx.x;
    if (b < nScat) {
        __shared__ int h[NB];
        __shared__ int base[NB];
        int e0 = b * 4096;
        for (int i = t; i < NB; i += 256) h[i] = 0;
        __syncthreads();
        int dloc[16];
#pragma unroll
        for (int u = 0; u < 16; ++u) {
            int e = e0 + u * 256 + t;
            dloc[u] = (e < E) ? dst[e] : -1;
            if (dloc[u] >= 0) atomicAdd(&h[(unsigned)dloc[u] >> 6], 1);
        }
        __syncthreads();
        for (int u = t; u < NB; u += 256)
            if (h[u] > 0) base[u] = u * CAP + atomicAdd(&gcur[u], h[u]);
        __syncthreads();
        for (int i = t; i < NB; i += 256) h[i] = 0;
        __syncthreads();
#pragma unroll
        for (int u = 0; u < 16; ++u) {
            int e = e0 + u * 256 + t;
            if (dloc[u] >= 0) {
                unsigned d = (unsigned)dloc[u];
                unsigned bk = d >> 6;
                unsigned ld = d & 63u;
                int k = atomicAdd(&h[bk], 1);
                ebuf[base[bk] + k] = (ld << 17) | (unsigned)src[e];
            }
        }
    } else if (b < nScat + nCast) {
        int i = ((b - nScat) * 256 + t) * 4;   // nCast*1024 == N*D0 exactly
        float4 v = *(const float4*)(x + i);
        unsigned o0 = (unsigned)f2bf(v.x) | ((unsigned)f2bf(v.y) << 16);
        unsigned o1 = (unsigned)f2bf(v.z) | ((unsigned)f2bf(v.w) << 16);
        uint2 pk; pk.x = o0; pk.y = o1;
        *(uint2*)(xh + i) = pk;
    } else if (b < nScat + nCast + 8) {
        int f = (b - nScat - nCast) * 4 + (t >> 6);   // 0..31
        int lane = t & 63;
        int nt = f & 7;
        int col = nt * 16 + (lane & 15);
        int kbase = (f >> 3) * 32 + (lane >> 4) * 8;
        unsigned short* o = wpk1 + ((size_t)f * 64 + lane) * 8;
#pragma unroll
        for (int j = 0; j < 8; ++j) {
            int k = kbase + j;
            float w = (k < 64) ? W1r[k * 128 + col] : W1l[(k - 64) * 128 + col];
            o[j] = f2bf(w);
        }
    } else {
        int f = (b - nScat - nCast - 8) * 4 + (t >> 6);   // 0..19
        if (f < 20) {
            int lane = t & 63;
            int nt = f % 5;
            int col = nt * 16 + (lane & 15);       // 0..79
            int kbase = (f / 5) * 32 + (lane >> 4) * 8;
            unsigned short* o = wpk2 + ((size_t)f * 64 + lane) * 8;
#pragma unroll
            for (int j = 0; j < 8; ++j) {
                int k = kbase + j;
                float w = (col < 40) ? W2l[k * 40 + col] : W2r[k * 40 + (col - 40)];
                o[j] = f2bf(w);
            }
        }
    }
}

// ---------------- fused fill + agg1 + GEMM1 + ReLU + GEMM2 (512 threads / 8 waves) --------
// One block per bucket == one 64-row tile. 8 waves: agg walks 8 nodes/wave (halved serial
// latency chain vs 4-wave version); GEMM splits 4 row-tiles x 2 col-halves across waves.
__global__ __launch_bounds__(512, 4) void fillagg1gemm_kernel(
        const unsigned short* __restrict__ xh, const unsigned* __restrict__ ebuf,
        const int* __restrict__ gcur,
        const unsigned short* __restrict__ Wpk1, const unsigned short* __restrict__ Wpk2,
        const float* __restrict__ b1, const float* __restrict__ b2,
        int* __restrict__ rowstart, int* __restrict__ rowcnt, int* __restrict__ csr,
        unsigned short* __restrict__ p2h, float* __restrict__ r2, int N) {
    __shared__ int csr_l[CAP];
    __shared__ int cnt[64];
    __shared__ int sd[64];
    __shared__ int rs[64];
    __shared__ int pos[64];
    __shared__ __align__(16) unsigned short As[64 * 136];  // [row][k], +8 pad
    int b = blockIdx.x, t = threadIdx.x;
    int r0 = b * 64;
    // stage xh rows into As[:, 0:64] (512 threads x one uint4 = 8 KB)
    {
        int r = t >> 3, c = t & 7;
        int gr = r0 + r; gr = (gr < N) ? gr : (N - 1);
        *(uint4*)(As + r * 136 + c * 8) = ((const uint4*)(xh + (size_t)gr * 64))[c];
    }
    int s0 = b * CAP;
    int ne = gcur[b]; ne = (ne < CAP) ? ne : CAP;
    unsigned ev[3];
#pragma unroll
    for (int u = 0; u < 3; ++u) {
        int i = t + u * 512;
        ev[u] = (i < ne) ? ebuf[s0 + i] : 0xFFFFFFFFu;
    }
    if (t < 64) cnt[t] = 0;
    __syncthreads();
#pragma unroll
    for (int u = 0; u < 3; ++u)
        if (ev[u] != 0xFFFFFFFFu) atomicAdd(&cnt[ev[u] >> 17], 1);
    __syncthreads();
    if (t < 64) sd[t] = cnt[t];
    __syncthreads();
    for (int off = 1; off < 64; off <<= 1) {
        int u = (t >= off && t < 64) ? sd[t - off] : 0;
        __syncthreads();
        if (t < 64) sd[t] += u;
        __syncthreads();
    }
    if (t < 64) {
        int ex = sd[t] - cnt[t];
        rs[t] = ex;
        pos[t] = ex;
    }
    __syncthreads();
#pragma unroll
    for (int u = 0; u < 3; ++u) {
        if (ev[u] != 0xFFFFFFFFu) {
            int ld = (int)(ev[u] >> 17);
            int p = atomicAdd(&pos[ld], 1);
            csr_l[p] = (int)(ev[u] & 0x1FFFFu);
        }
    }
    if (t < 64) {
        int node = r0 + t;
        if (node < N) {
            rowstart[node] = s0 + rs[t];
            rowcnt[node] = cnt[t];
        }
    }
    __syncthreads();
    for (int i = t; i < ne; i += 512) csr[s0 + i] = csr_l[i];

    // ---- aggregate this bucket's 64 nodes: 8 waves x 8 nodes, register accumulators ----
    int w = t >> 6, lane = t & 63;
    int l = lane & 7, g = lane >> 3;
    for (int n = w; n < 64; n += 8) {
        int node = r0 + n;
        if (node >= N) break;
        int beg = rs[n];
        int deg = cnt[n];
        float acc[8];
#pragma unroll
        for (int k = 0; k < 8; ++k) acc[k] = 0.f;
        int jmax = (deg + 7) >> 3;
        int full = jmax - 1;
        int j = 0;
        for (; j + 2 <= full; j += 2) {
            int s0e = csr_l[beg + j * 8 + g];
            int s1e = csr_l[beg + (j + 1) * 8 + g];
            uint4 v0 = *(const uint4*)(xh + (size_t)s0e * D0 + l * 8);
            uint4 v1 = *(const uint4*)(xh + (size_t)s1e * D0 + l * 8);
            acc[0] += __uint_as_float(v0.x << 16);  acc[1] += __uint_as_float(v0.x & 0xffff0000u);
            acc[2] += __uint_as_float(v0.y << 16);  acc[3] += __uint_as_float(v0.y & 0xffff0000u);
            acc[4] += __uint_as_float(v0.z << 16);  acc[5] += __uint_as_float(v0.z & 0xffff0000u);
            acc[6] += __uint_as_float(v0.w << 16);  acc[7] += __uint_as_float(v0.w & 0xffff0000u);
            acc[0] += __uint_as_float(v1.x << 16);  acc[1] += __uint_as_float(v1.x & 0xffff0000u);
            acc[2] += __uint_as_float(v1.y << 16);  acc[3] += __uint_as_float(v1.y & 0xffff0000u);
            acc[4] += __uint_as_float(v1.z << 16);  acc[5] += __uint_as_float(v1.z & 0xffff0000u);
            acc[6] += __uint_as_float(v1.w << 16);  acc[7] += __uint_as_float(v1.w & 0xffff0000u);
        }
        if (j < full) {
            int s0e = csr_l[beg + j * 8 + g];
            uint4 v0 = *(const uint4*)(xh + (size_t)s0e * D0 + l * 8);
            acc[0] += __uint_as_float(v0.x << 16);  acc[1] += __uint_as_float(v0.x & 0xffff0000u);
            acc[2] += __uint_as_float(v0.y << 16);  acc[3] += __uint_as_float(v0.y & 0xffff0000u);
            acc[4] += __uint_as_float(v0.z << 16);  acc[5] += __uint_as_float(v0.z & 0xffff0000u);
            acc[6] += __uint_as_float(v0.w << 16);  acc[7] += __uint_as_float(v0.w & 0xffff0000u);
        }
        if (jmax > 0) {
            int slot = full * 8 + g;
            int e = beg + ((slot < deg) ? slot : (deg - 1));
            int s0e = csr_l[e];
            float wgt = (slot < deg) ? 1.f : 0.f;
            uint4 v0 = *(const uint4*)(xh + (size_t)s0e * D0 + l * 8);
            acc[0] = fmaf(wgt, __uint_as_float(v0.x << 16), acc[0]);
            acc[1] = fmaf(wgt, __uint_as_float(v0.x & 0xffff0000u), acc[1]);
            acc[2] = fmaf(wgt, __uint_as_float(v0.y << 16), acc[2]);
            acc[3] = fmaf(wgt, __uint_as_float(v0.y & 0xffff0000u), acc[3]);
            acc[4] = fmaf(wgt, __uint_as_float(v0.z << 16), acc[4]);
            acc[5] = fmaf(wgt, __uint_as_float(v0.z & 0xffff0000u), acc[5]);
            acc[6] = fmaf(wgt, __uint_as_float(v0.w << 16), acc[6]);
            acc[7] = fmaf(wgt, __uint_as_float(v0.w & 0xffff0000u), acc[7]);
        }
#pragma unroll
        for (int off = 8; off <= 32; off <<= 1) {
#pragma unroll
            for (int k = 0; k < 8; ++k) acc[k] += __shfl_xor(acc[k], off);
        }
        float inv = 1.f / (float)max(deg, 1);
        if (g == 0) {   // write bf16 mean straight into A-tile cols 64..127
            unsigned o0 = (unsigned)f2bf(acc[0] * inv) | ((unsigned)f2bf(acc[1] * inv) << 16);
            unsigned o1 = (unsigned)f2bf(acc[2] * inv) | ((unsigned)f2bf(acc[3] * inv) << 16);
            unsigned o2 = (unsigned)f2bf(acc[4] * inv) | ((unsigned)f2bf(acc[5] * inv) << 16);
            unsigned o3 = (unsigned)f2bf(acc[6] * inv) | ((unsigned)f2bf(acc[7] * inv) << 16);
            uint4 pk; pk.x = o0; pk.y = o1; pk.z = o2; pk.w = o3;
            *(uint4*)(As + n * 136 + 64 + l * 8) = pk;
        }
    }
    __syncthreads();

    // ---- GEMM phase 1: [x|agg] @ [W1r;W1l]; wave w: row-tile rt=w>>1, col-half=w&1 ----
    int rt = w >> 1, half = w & 1;
    int l15 = lane & 15, q = lane >> 4;
    f32x4 zero = {0.f, 0.f, 0.f, 0.f};
    const unsigned short* abase = As + (rt * 16 + l15) * 136 + q * 8;
    f32x4 acc1[4];
#pragma unroll
    for (int nti = 0; nti < 4; ++nti) acc1[nti] = zero;
#pragma unroll
    for (int ks = 0; ks < 4; ++ks) {
        s16x8 a0 = *(const s16x8*)(abase + ks * 32);
        s16x8 bb[4];
#pragma unroll
        for (int nti = 0; nti < 4; ++nti) {
            int nt = half * 4 + nti;
            bb[nti] = *(const s16x8*)(Wpk1 + ((size_t)(ks * 8 + nt) * 64 + lane) * 8);
        }
#pragma unroll
        for (int nti = 0; nti < 4; ++nti)
            acc1[nti] = __builtin_amdgcn_mfma_f32_16x16x32_bf16(a0, bb[nti], acc1[nti], 0, 0, 0);
    }
    __syncthreads();   // all waves done READING As rows before cross-wave staging writes
    // stage h = relu(acc + b1): wave w writes rows rt*16.., cols half*64..half*64+63
    int rloc = rt * 16 + q * 4;
#pragma unroll
    for (int nti = 0; nti < 4; ++nti) {
        int col = (half * 4 + nti) * 16 + l15;
        float bias = b1[col];
#pragma unroll
        for (int reg = 0; reg < 4; ++reg)
            As[(rloc + reg) * 136 + col] = f2bf(fmaxf(acc1[nti][reg] + bias, 0.f));
    }
    __syncthreads();   // full h-rows visible before phase 2 reads
    // ---- GEMM phase 2: h @ [W2l|W2r]; wave w: row-tile rt, col-tiles half*3+{0..2} -------
    f32x4 acc2[3];
#pragma unroll
    for (int nti = 0; nti < 3; ++nti) acc2[nti] = zero;
#pragma unroll
    for (int ks = 0; ks < 4; ++ks) {
        s16x8 a0 = *(const s16x8*)(abase + ks * 32);
        s16x8 bb[3];
#pragma unroll
        for (int nti = 0; nti < 3; ++nti) {
            int nt = half * 3 + nti;
            if (nt < 5)
                bb[nti] = *(const s16x8*)(Wpk2 + ((size_t)(ks * 5 + nt) * 64 + lane) * 8);
        }
#pragma unroll
        for (int nti = 0; nti < 3; ++nti) {
            int nt = half * 3 + nti;
            if (nt < 5)
                acc2[nti] = __builtin_amdgcn_mfma_f32_16x16x32_bf16(a0, bb[nti], acc2[nti], 0, 0, 0);
        }
    }
    int rbase = r0 + rt * 16 + q * 4;
#pragma unroll
    for (int nti = 0; nti < 3; ++nti) {
        int nt = half * 3 + nti;
        if (nt < 5) {
            int col = nt * 16 + l15;   // 0..79
            bool isp = col < 40;
            int oc = isp ? col : (col - 40);
            float bias = isp ? 0.f : b2[oc];
#pragma unroll
            for (int reg = 0; reg < 4; ++reg) {
                int row = rbase + reg;
                if (row < N) {
                    float v = acc2[nti][reg] + bias;
                    if (isp) p2h[(size_t)row * 64 + oc] = f2bf(v);
                    else     r2[(size_t)row * D2 + oc] = v;
                }
            }
        }
    }
}

// ---------------- agg2 + log_softmax: 5 lanes/edge x uint4, 12 edges/instr ----------------
// p2h rows padded to 64 shorts (128 B) -> every edge gather = exactly one cache line

__global__ void agg2_kernel(const unsigned short* __restrict__ p2h, const float* __restrict__ r2,
                            const int* __restrict__ rowstart, const int* __restrict__ rowcnt,
                            const int* __restrict__ csr,
                            float* __restrict__ out, float* __restrict__ out2, int N) {
    int wid = (blockIdx.x * blockDim.x + threadIdx.x) >> 6;
    int lane = threadIdx.x & 63;
    if (wid >= N) return;
    int beg = rowstart[wid];
    int deg = rowcnt[wid];
    int g = lane / 5;             // 0..12 (g==12: lanes 60..63 idle)
    int l = lane - g * 5;         // 0..4
    bool gv = g < 12;
    float a[8];
#pragma unroll
    for (int k = 0; k < 8; ++k) a[k] = 0.f;
    int jmax = (deg + 11) / 12;
    int full = jmax - 1;
    int j = 0;
    for (; j + 2 <= full; j += 2) {
        int s0 = csr[beg + j * 12 + g];
        int s1 = csr[beg + (j + 1) * 12 + g];
        uint4 v0 = *(const uint4*)(p2h + (size_t)s0 * 64 + l * 8);
        uint4 v1 = *(const uint4*)(p2h + (size_t)s1 * 64 + l * 8);
        if (gv) {
            a[0] += __uint_as_float(v0.x << 16);  a[1] += __uint_as_float(v0.x & 0xffff0000u);
            a[2] += __uint_as_float(v0.y << 16);  a[3] += __uint_as_float(v0.y & 0xffff0000u);
            a[4] += __uint_as_float(v0.z << 16);  a[5] += __uint_as_float(v0.z & 0xffff0000u);
            a[6] += __uint_as_float(v0.w << 16);  a[7] += __uint_as_float(v0.w & 0xffff0000u);
            a[0] += __uint_as_float(v1.x << 16);  a[1] += __uint_as_float(v1.x & 0xffff0000u);
            a[2] += __uint_as_float(v1.y << 16);  a[3] += __uint_as_float(v1.y & 0xffff0000u);
            a[4] += __uint_as_float(v1.z << 16);  a[5] += __uint_as_float(v1.z & 0xffff0000u);
            a[6] += __uint_as_float(v1.w << 16);  a[7] += __uint_as_float(v1.w & 0xffff0000u);
        }
    }
    if (j < full) {
        int s0 = csr[beg + j * 12 + g];
        uint4 v0 = *(const uint4*)(p2h + (size_t)s0 * 64 + l * 8);
        if (gv) {
            a[0] += __uint_as_float(v0.x << 16);  a[1] += __uint_as_float(v0.x & 0xffff0000u);
            a[2] += __uint_as_float(v0.y << 16);  a[3] += __uint_as_float(v0.y & 0xffff0000u);
            a[4] += __uint_as_float(v0.z << 16);  a[5] += __uint_as_float(v0.z & 0xffff0000u);
            a[6] += __uint_as_float(v0.w << 16);  a[7] += __uint_as_float(v0.w & 0xffff0000u);
        }
    }
    if (jmax > 0) {
        int slot = full * 12 + g;
        int e = beg + ((slot < deg) ? slot : (deg - 1));
        int s0 = csr[e];
        float w = (gv && slot < deg) ? 1.f : 0.f;
        uint4 v0 = *(const uint4*)(p2h + (size_t)s0 * 64 + l * 8);
        a[0] = fmaf(w, __uint_as_float(v0.x << 16), a[0]);
        a[1] = fmaf(w, __uint_as_float(v0.x & 0xffff0000u), a[1]);
        a[2] = fmaf(w, __uint_as_float(v0.y << 16), a[2]);
        a[3] = fmaf(w, __uint_as_float(v0.y & 0xffff0000u), a[3]);
        a[4] = fmaf(w, __uint_as_float(v0.z << 16), a[4]);
        a[5] = fmaf(w, __uint_as_float(v0.z & 0xffff0000u), a[5]);
        a[6] = fmaf(w, __uint_as_float(v0.w << 16), a[6]);
        a[7] = fmaf(w, __uint_as_float(v0.w & 0xffff0000u), a[7]);
    }
    {
        float b0;
#pragma unroll
        for (int k = 0; k < 8; ++k) { b0 = __shfl(a[k], lane + 30); if (g < 6) a[k] += b0; }
#pragma unroll
        for (int k = 0; k < 8; ++k) { b0 = __shfl(a[k], lane + 15); if (g < 3) a[k] += b0; }
#pragma unroll
        for (int k = 0; k < 8; ++k) {
            float c1 = __shfl(a[k], lane + 5);
            float c2 = __shfl(a[k], lane + 10);
            if (g == 0) a[k] += c1 + c2;
        }
    }
    float inv = 1.f / (float)max(deg, 1);
    bool wr = (lane < 5);
    float h2[8];
    if (wr) {
        float4 ra = *(const float4*)(r2 + (size_t)wid * D2 + lane * 8);
        float4 rb = *(const float4*)(r2 + (size_t)wid * D2 + lane * 8 + 4);
        h2[0] = ra.x + a[0] * inv; h2[1] = ra.y + a[1] * inv;
        h2[2] = ra.z + a[2] * inv; h2[3] = ra.w + a[3] * inv;
        h2[4] = rb.x + a[4] * inv; h2[5] = rb.y + a[5] * inv;
        h2[6] = rb.z + a[6] * inv; h2[7] = rb.w + a[7] * inv;
        float4 oa; oa.x = h2[0]; oa.y = h2[1]; oa.z = h2[2]; oa.w = h2[3];
        float4 ob; ob.x = h2[4]; ob.y = h2[5]; ob.z = h2[6]; ob.w = h2[7];
        *(float4*)(out + (size_t)wid * D2 + lane * 8) = oa;
        *(float4*)(out + (size_t)wid * D2 + lane * 8 + 4) = ob;
    }
    float m = -INFINITY;
    if (wr) {
#pragma unroll
        for (int k = 0; k < 8; ++k) m = fmaxf(m, h2[k]);
    }
#pragma unroll
    for (int off = 1; off < 64; off <<= 1) m = fmaxf(m, __shfl_xor(m, off));
    float s = 0.f;
    if (wr) {
#pragma unroll
        for (int k = 0; k < 8; ++k) s += expf(h2[k] - m);
    }
#pragma unroll
    for (int off = 1; off < 64; off <<= 1) s += __shfl_xor(s, off);
    if (wr) {
        float lg = m + logf(s);
        float4 oa; oa.x = h2[0] - lg; oa.y = h2[1] - lg; oa.z = h2[2] - lg; oa.w = h2[3] - lg;
        float4 ob; ob.x = h2[4] - lg; ob.y = h2[5] - lg; ob.z = h2[6] - lg; ob.w = h2[7] - lg;
        *(float4*)(out2 + (size_t)wid * D2 + lane * 8) = oa;
        *(float4*)(out2 + (size_t)wid * D2 + lane * 8 + 4) = ob;
    }
}

// ---------------- launch ----------------

extern "C" void kernel_launch(void* const* d_in, const int* in_sizes, int n_in,
                              void* d_out, int out_size, void* d_ws, size_t ws_size,
                              hipStream_t stream) {
    const float* x   = (const float*)d_in[0];
    const int*   ei  = (const int*)d_in[1];
    const float* W1l = (const float*)d_in[2];
    const float* W1r = (const float*)d_in[3];
    const float* b1  = (const float*)d_in[4];
    const float* W2l = (const float*)d_in[5];
    const float* W2r = (const float*)d_in[6];
    const float* b2  = (const float*)d_in[7];
    float* out = (float*)d_out;

    const int N = N_NODES;
    const int E = in_sizes[1] / 2;
    const int* src = ei;
    const int* dst = ei + E;

    char* p = (char*)d_ws;
    auto alloc = [&](size_t bytes) -> void* {
        void* r = (void*)p;
        p += (bytes + 255) & ~(size_t)255;
        return r;
    };
    const int nScat = (E + 4095) / 4096;           // 196
    const int nCast = (N * D0) / 1024;             // 3125 (exact)

    unsigned* ebuf     = (unsigned*)alloc((size_t)NB * CAP * 4);   // ~4 MB
    int*      csr      = (int*)alloc((size_t)NB * CAP * 4);        // ~4 MB
    int*      gcur     = (int*)alloc(NB * 4);
    int*      rowstart = (int*)alloc((size_t)N * 4);
    int*      rowcnt   = (int*)alloc((size_t)N * 4);
    unsigned short* xh    = (unsigned short*)alloc((size_t)N * D0 * 2);
    unsigned short* wpk1  = (unsigned short*)alloc((size_t)32 * 64 * 8 * 2);
    unsigned short* wpk2  = (unsigned short*)alloc((size_t)20 * 64 * 8 * 2);
    unsigned short* p2h   = (unsigned short*)alloc((size_t)N * 64 * 2);   // 128 B stride
    float* r2buf = (float*)alloc((size_t)N * D2 * 4);

    // zero bucket cursors, then fused prep (LDS-aggregated scatter + cast + pack)
    hipMemsetAsync(gcur, 0, NB * sizeof(int), stream);
    prep_scatter_kernel<<<nScat + nCast + 8 + 5, 256, 0, stream>>>(
        x, src, dst, W1l, W1r, W2l, W2r, xh, gcur, ebuf, wpk1, wpk2, E, nScat, nCast);

    // fused per-bucket fill + layer-1 aggregation + GEMM1 + ReLU + GEMM2 (8 waves/block)
    fillagg1gemm_kernel<<<NB, 512, 0, stream>>>(xh, ebuf, gcur, wpk1, wpk2, b1, b2,
                                                rowstart, rowcnt, csr, p2h, r2buf, N);

    // layer-2 aggregation of projected features + fused log_softmax
    agg2_kernel<<<(N * 64 + 255) / 256, 256, 0, stream>>>(p2h, r2buf, rowstart, rowcnt, csr,
                                                          out, out + (size_t)N * D2, N);
}